// Round 7
// baseline (203.778 us; speedup 1.0000x reference)
//
#include <hip/hip_runtime.h>
#include <hip/hip_bf16.h>
#include <stdint.h>
#include <stddef.h>

// ---------------------------------------------------------------------------
// FixedEmbedderNN — round 7: gather served from LDS (DS pipe), not L1/L2.
// Evidence: rounds 2/5/6 pinned at ~90-97us across 3 gather structures with
// identical L1-miss-line counts -> L1 MSHR throughput bound (~8cyc/64B line).
// Fix: block = 1/CU (512thr, 8 waves, 384 rows). tcat (256KB) staged in two
// column-half passes (125KB each) into LDS; gathers become ds_read_b128.
// Bank spread via idx-dependent 16B-slot rotation baked into the global
// table layout (pre2): col j=16t+4g+r -> half h=t>>2, u=(t>>1)&1, v=t&1,
//   slot=(u*4+g+c)&7, elem=v*4+r; addr = ((h*20+f)*50+c)*64 + slot*8 + elem.
// Pass A: cols 0-63 (acc t0-3), pass B: cols 64-127 (acc t4-7); idx packed in
// VGPRs between passes; LN0 wave-local; GEMM tail = round-5 code per group,
// hbuf aliases the dead table region.
// ---------------------------------------------------------------------------

typedef __attribute__((ext_vector_type(8))) short short8;
typedef __attribute__((ext_vector_type(4))) float f32x4;
typedef __attribute__((ext_vector_type(2))) uint32_t uint32x2;

#define LN_EPS 1e-5f

__device__ __forceinline__ float bflo(uint32_t u){ union{uint32_t u;float f;} c; c.u = u<<16; return c.f; }
__device__ __forceinline__ float bfhi(uint32_t u){ union{uint32_t u;float f;} c; c.u = u&0xffff0000u; return c.f; }
__device__ __forceinline__ uint16_t f2bf(float f){
  union{ __hip_bfloat16 h; uint16_t u; } c; c.h = __float2bfloat16(f); return c.u;
}
__device__ __forceinline__ uint32_t pkbf(float lo, float hi){
  return (uint32_t)f2bf(lo) | ((uint32_t)f2bf(hi)<<16);
}

// ---------------- precompute kernel 1 (no deps) ----------------
__global__ __launch_bounds__(128) void pre1(
    const float* __restrict__ W_num, const float* __restrict__ b_num,
    const float* __restrict__ W_in,  const float* __restrict__ b_in,
    const float* __restrict__ W1,    const float* __restrict__ b1,
    const float* __restrict__ W2,    const float* __restrict__ b2,
    const float* __restrict__ W_out, const float* __restrict__ b_out,
    const float* __restrict__ ln_g,  const float* __restrict__ ln_b,
    float* __restrict__ WLf,    // [2][128][128]
    float* __restrict__ Bnum,   // [21][128]
    float* __restrict__ bfold,  // [2][128]
    uint16_t* __restrict__ woutp, // Wout' transposed pack [(t*4+ks)*64+lane][8]
    float* __restrict__ boutp)    // bout' permuted [g*32+t*4+r]
{
  const int b = blockIdx.x, j = threadIdx.x;
  if (b < 256) {                       // WL = W1@W2 per layer
    const int l = b >> 7, k = b & 127;
    const float* w1r = W1 + (l*128 + k)*256;
    const float* w2  = W2 + l*256*128;
    float s = 0.f;
    for (int m = 0; m < 256; m++) s = fmaf(w1r[m], w2[m*128 + j], s);
    WLf[(l*128 + k)*128 + j] = s;
  } else if (b < 277) {                // Bnum rows
    const int r = b - 256;
    if (r < 20) {
      const float* wn = W_num + r*32;
      const float* wi = W_in + (size_t)(20 + r)*32*128;
      float s = 0.f;
      for (int e = 0; e < 32; e++) s = fmaf(wn[e], wi[e*128 + j], s);
      Bnum[r*128 + j] = s;
    } else {
      float s = b_in[j];
      for (int f = 0; f < 20; f++) {
        const float* bn = b_num + f*32;
        const float* wi = W_in + (size_t)(20 + f)*32*128;
        for (int e = 0; e < 32; e++) s = fmaf(bn[e], wi[e*128 + j], s);
      }
      Bnum[20*128 + j] = s;
    }
  } else if (b < 279) {                // bfold = b1@W2 + b2
    const int l = b - 277;
    const float* b1r = b1 + l*256;
    const float* w2  = W2 + l*256*128;
    float s = b2[l*128 + j];
    for (int k = 0; k < 256; k++) s = fmaf(b1r[k], w2[k*128 + j], s);
    bfold[l*128 + j] = s;
  } else if (b < 311) {                // woutp: Wout' = diag(g1)@W_out, transposed A-pack
    const int p = b - 279, t = p >> 2, ks = p & 3;
    const int lane = j & 63, rep = j >> 6;
    const int col = 16*t + (lane & 15);
    for (int ii = 0; ii < 4; ii++) {
      const int i = rep*4 + ii;
      const int k = 32*ks + 8*(lane >> 4) + i;
      woutp[((t*4 + ks)*64 + lane)*8 + i] = f2bf(ln_g[128 + k] * W_out[k*128 + col]);
    }
  } else {                             // boutp (permuted): b1n@W_out + b_out
    const int t = (j >> 2) & 7, g = j >> 5, r = j & 3;
    const int col = 16*t + 4*g + r;
    float s = b_out[col];
    for (int k = 0; k < 128; k++) s = fmaf(ln_b[128 + k], W_out[k*128 + col], s);
    boutp[j] = s;
  }
}

// ---------------- precompute kernel 2 (depends on pre1) ----------------
__global__ __launch_bounds__(128) void pre2(
    const float* __restrict__ emb, const float* __restrict__ W_in,
    const float* __restrict__ ln_g, const float* __restrict__ ln_b,
    const float* __restrict__ WLf, const float* __restrict__ Bnum,
    const float* __restrict__ bfold,
    uint16_t* __restrict__ tcatp, // [2 halves][20][50][64] bf16, slot-rotated
    uint16_t* __restrict__ wl2p,  // WL1' transposed pack
    float* __restrict__ bf1p,     // bf1' permuted
    uint16_t* __restrict__ a1p)   // A1^T A-frag pack [t*64+lane][8]
{
  const int b = blockIdx.x, j = threadIdx.x;
  __shared__ float sh[128];
  if (b < 1000) {                      // Tcat1 = emb@W_in_slice@WL_0, rotated store
    const int f = b / 50, c = b % 50;
    const float* e  = emb + (f*50 + c)*32;
    const float* wi = W_in + (size_t)f*32*128;
    float s = 0.f;
    for (int k = 0; k < 32; k++) s = fmaf(e[k], wi[k*128 + j], s);
    sh[j] = s;
    __syncthreads();
    float s2 = 0.f;
    for (int k = 0; k < 128; k++) s2 = fmaf(sh[k], WLf[k*128 + j], s2);
    // col j = 16t+4g+r: h=t>>2, u=(t>>1)&1, v=t&1; slot=(u*4+g+c)&7, e=v*4+r
    const int t = j >> 4, g = (j >> 2) & 3, r = j & 3;
    const int h = t >> 2, u = (t >> 1) & 1, v = t & 1;
    const int slot = (u*4 + g + c) & 7;
    tcatp[((h*20 + f)*50 + c)*64 + slot*8 + v*4 + r] = f2bf(s2);
  } else if (b < 1032) {               // wl2p: WL1' = diag(g0)@WL_1, transposed A-pack
    const int p = b - 1000, t = p >> 2, ks = p & 3;
    const int lane = j & 63, rep = j >> 6;
    const int col = 16*t + (lane & 15);
    const float* wl1 = WLf + 16384;
    for (int ii = 0; ii < 4; ii++) {
      const int i = rep*4 + ii;
      const int k = 32*ks + 8*(lane >> 4) + i;
      wl2p[((t*4 + ks)*64 + lane)*8 + i] = f2bf(ln_g[k] * wl1[k*128 + col]);
    }
  } else if (b == 1032) {              // bf1p (permuted): b0@WL_1 + bfold_1
    const int t = (j >> 2) & 7, g = j >> 5, r = j & 3;
    const int col = 16*t + 4*g + r;
    const float* wl1 = WLf + 16384;
    float s = bfold[128 + col];
    for (int k = 0; k < 128; k++) s = fmaf(ln_b[k], wl1[k*128 + col], s);
    bf1p[j] = s;
  } else {                             // a1p: A1[k][col] = Bnum[k]@WL_0 (+bfold0 @k==20)
    const int t = b - 1033;
    const int lane = j & 63, rep = j >> 6;
    const int col = 16*t + (lane & 15);
    for (int ii = 0; ii < 4; ii++) {
      const int i = rep*4 + ii;
      const int k = 8*(lane >> 4) + i;
      float v = 0.f;
      if (k <= 20) {
        if (k == 20) v = bfold[col];
        for (int m = 0; m < 128; m++) v = fmaf(Bnum[k*128 + m], WLf[m*128 + col], v);
      }
      a1p[(t*64 + lane)*8 + i] = f2bf(v);
    }
  }
}

// ---------------- main fused kernel ----------------
// 256 blocks (1/CU), 512 threads (8 waves). Block owns 384 rows; wave owns 48
// rows = 3 groups of 16. Table half staged in LDS; 2 gather passes.
__global__ __launch_bounds__(512, 2) void fused_main(
    const float* __restrict__ x,
    const uint16_t* __restrict__ tcatp,
    const uint16_t* __restrict__ a1p,
    const uint16_t* __restrict__ wl2p,
    const uint16_t* __restrict__ woutp,
    const float* __restrict__ bf1p,
    const float* __restrict__ boutp,
    float* __restrict__ out)
{
  __shared__ uint4 tbl4[8000];                 // 128000B half-table; GEMM hbuf aliases
  __shared__ float xs[8*16*41];                // per-wave x scratch (pass A only)
  const int tid = threadIdx.x, lane = tid & 63, w = tid >> 6;
  const int g = lane >> 4, c16 = lane & 15;
  const char* tbl = (const char*)tbl4;

  // ---- stage half 0 (cols 0..63): linear 128000B copy ----
  {
    const uint4* s0 = reinterpret_cast<const uint4*>(tcatp);
    for (int i = tid; i < 8000; i += 512) tbl4[i] = s0[i];
  }
  __syncthreads();

  uint32_t idxp[3][5];     // 20 idx packed 4-per-u32, per group
  short8 xf[3];
  f32x4 accA[3][4], accB[3][4];

  // ================= pass A: cols 0-63 =================
  #pragma unroll
  for (int gr = 0; gr < 3; gr++) {
    const int rowbase = blockIdx.x*384 + (w*3 + gr)*16;
    float* xw = xs + w*16*41;
    {
      const float* xsrc = x + (size_t)rowbase*40;
      #pragma unroll
      for (int k = 0; k < 10; k++) {
        const int i = k*64 + lane;
        xw[(i/40)*41 + (i%40)] = xsrc[i];
      }
    }
    asm volatile("s_waitcnt lgkmcnt(0)" ::: "memory");
    const float* xr = xw + c16*41;

    // pack categorical codes (u8 x4 per word)
    #pragma unroll
    for (int wd = 0; wd < 5; wd++) {
      uint32_t p = 0;
      #pragma unroll
      for (int b2 = 0; b2 < 4; b2++) p |= ((uint32_t)(int)xr[wd*4 + b2]) << (8*b2);
      idxp[gr][wd] = p;
    }
    // numeric fragment
    #pragma unroll
    for (int i = 0; i < 8; i++) {
      const int k = 8*g + i;
      const float v = (k < 20) ? xr[20 + k] : (k == 20 ? 1.0f : 0.0f);
      ((uint16_t*)&xf[gr])[i] = f2bf(v);
    }
    // numeric MFMA t0..3
    #pragma unroll
    for (int t = 0; t < 4; t++) {
      const short8 af = *reinterpret_cast<const short8*>(a1p + (t*64 + lane)*8);
      accA[gr][t] = __builtin_amdgcn_mfma_f32_16x16x32_bf16(af, xf[gr],
                      (f32x4){0.f,0.f,0.f,0.f}, 0, 0, 0);
    }
    // gather from LDS (slot-rotated)
    #pragma unroll
    for (int f = 0; f < 20; f++) {
      const int idx = (int)((idxp[gr][f >> 2] >> (8*(f & 3))) & 0xffu);
      const char* p = tbl + (f*50 + idx)*128;
      const uint4 u0 = *reinterpret_cast<const uint4*>(p + (((g + idx) & 7) << 4));
      const uint4 u1 = *reinterpret_cast<const uint4*>(p + (((g + idx + 4) & 7) << 4));
      accA[gr][0][0] += bflo(u0.x); accA[gr][0][1] += bfhi(u0.x);
      accA[gr][0][2] += bflo(u0.y); accA[gr][0][3] += bfhi(u0.y);
      accA[gr][1][0] += bflo(u0.z); accA[gr][1][1] += bfhi(u0.z);
      accA[gr][1][2] += bflo(u0.w); accA[gr][1][3] += bfhi(u0.w);
      accA[gr][2][0] += bflo(u1.x); accA[gr][2][1] += bfhi(u1.x);
      accA[gr][2][2] += bflo(u1.y); accA[gr][2][3] += bfhi(u1.y);
      accA[gr][3][0] += bflo(u1.z); accA[gr][3][1] += bfhi(u1.z);
      accA[gr][3][2] += bflo(u1.w); accA[gr][3][3] += bfhi(u1.w);
    }
  }
  __syncthreads();                       // all pass-A table reads done

  // ---- stage half 1 (cols 64..127) ----
  {
    const uint4* s1 = reinterpret_cast<const uint4*>(tcatp + 64000);
    for (int i = tid; i < 8000; i += 512) tbl4[i] = s1[i];
  }
  __syncthreads();

  // ================= pass B: cols 64-127 =================
  #pragma unroll
  for (int gr = 0; gr < 3; gr++) {
    #pragma unroll
    for (int t = 0; t < 4; t++) {
      const short8 af = *reinterpret_cast<const short8*>(a1p + ((t + 4)*64 + lane)*8);
      accB[gr][t] = __builtin_amdgcn_mfma_f32_16x16x32_bf16(af, xf[gr],
                      (f32x4){0.f,0.f,0.f,0.f}, 0, 0, 0);
    }
    #pragma unroll
    for (int f = 0; f < 20; f++) {
      const int idx = (int)((idxp[gr][f >> 2] >> (8*(f & 3))) & 0xffu);
      const char* p = tbl + (f*50 + idx)*128;
      const uint4 u0 = *reinterpret_cast<const uint4*>(p + (((g + idx) & 7) << 4));
      const uint4 u1 = *reinterpret_cast<const uint4*>(p + (((g + idx + 4) & 7) << 4));
      accB[gr][0][0] += bflo(u0.x); accB[gr][0][1] += bfhi(u0.x);
      accB[gr][0][2] += bflo(u0.y); accB[gr][0][3] += bfhi(u0.y);
      accB[gr][1][0] += bflo(u0.z); accB[gr][1][1] += bfhi(u0.z);
      accB[gr][1][2] += bflo(u0.w); accB[gr][1][3] += bfhi(u0.w);
      accB[gr][2][0] += bflo(u1.x); accB[gr][2][1] += bfhi(u1.x);
      accB[gr][2][2] += bflo(u1.y); accB[gr][2][3] += bfhi(u1.y);
      accB[gr][3][0] += bflo(u1.z); accB[gr][3][1] += bfhi(u1.z);
      accB[gr][3][2] += bflo(u1.w); accB[gr][3][3] += bfhi(u1.w);
    }
  }
  __syncthreads();                       // table dead -> hbuf may alias it

  // ================= LN0 + GEMM tail, per group =================
  uint16_t* hb = reinterpret_cast<uint16_t*>(tbl4) + w*(16*136);
  #pragma unroll
  for (int gr = 0; gr < 3; gr++) {
    const int rowbase = blockIdx.x*384 + (w*3 + gr)*16;

    // ---- LN0 (wave-local, 4 lanes per row) ----
    float s = 0.f;
    #pragma unroll
    for (int t = 0; t < 4; t++)
      #pragma unroll
      for (int r = 0; r < 4; r++) s += accA[gr][t][r] + accB[gr][t][r];
    s += __shfl_xor(s, 16); s += __shfl_xor(s, 32);
    const float mu = s * (1.f/128.f);
    float qv = 0.f;
    #pragma unroll
    for (int t = 0; t < 4; t++)
      #pragma unroll
      for (int r = 0; r < 4; r++) {
        const float dA = accA[gr][t][r] - mu; qv = fmaf(dA, dA, qv);
        const float dB = accB[gr][t][r] - mu; qv = fmaf(dB, dB, qv);
      }
    qv += __shfl_xor(qv, 16); qv += __shfl_xor(qv, 32);
    const float rs = rsqrtf(qv*(1.f/128.f) + LN_EPS);

    #pragma unroll
    for (int t = 0; t < 4; t++) {
      const uint32x2 vA = { pkbf((accA[gr][t][0]-mu)*rs, (accA[gr][t][1]-mu)*rs),
                            pkbf((accA[gr][t][2]-mu)*rs, (accA[gr][t][3]-mu)*rs) };
      *reinterpret_cast<uint32x2*>(hb + c16*136 + 16*t + 4*g) = vA;
      const uint32x2 vB = { pkbf((accB[gr][t][0]-mu)*rs, (accB[gr][t][1]-mu)*rs),
                            pkbf((accB[gr][t][2]-mu)*rs, (accB[gr][t][3]-mu)*rs) };
      *reinterpret_cast<uint32x2*>(hb + c16*136 + 16*(t + 4) + 4*g) = vB;
    }
    asm volatile("s_waitcnt lgkmcnt(0)" ::: "memory");

    // ---- GEMM2': acc2 = z1 @ WL1' (+bf1') ----
    short8 a2[4];
    #pragma unroll
    for (int ks = 0; ks < 4; ks++)
      a2[ks] = *reinterpret_cast<const short8*>(hb + c16*136 + 32*ks + 8*g);
    f32x4 acc2[8];
    #pragma unroll
    for (int t = 0; t < 8; t++) {
      acc2[t] = *reinterpret_cast<const f32x4*>(bf1p + g*32 + t*4);
      #pragma unroll
      for (int ks = 0; ks < 4; ks++) {
        const short8 wf = *reinterpret_cast<const short8*>(wl2p + ((t*4 + ks)*64 + lane)*8);
        acc2[t] = __builtin_amdgcn_mfma_f32_16x16x32_bf16(wf, a2[ks], acc2[t], 0, 0, 0);
      }
    }

    // ---- LN1 ----
    float s2 = 0.f;
    #pragma unroll
    for (int t = 0; t < 8; t++) { s2 += acc2[t][0]+acc2[t][1]+acc2[t][2]+acc2[t][3]; }
    s2 += __shfl_xor(s2, 16); s2 += __shfl_xor(s2, 32);
    const float mu2 = s2 * (1.f/128.f);
    float q2 = 0.f;
    #pragma unroll
    for (int t = 0; t < 8; t++)
      #pragma unroll
      for (int r = 0; r < 4; r++) { const float d = acc2[t][r]-mu2; q2 = fmaf(d, d, q2); }
    q2 += __shfl_xor(q2, 16); q2 += __shfl_xor(q2, 32);
    const float rs2 = rsqrtf(q2*(1.f/128.f) + LN_EPS);

    asm volatile("s_waitcnt lgkmcnt(0)" ::: "memory");   // a2 reads done
    #pragma unroll
    for (int t = 0; t < 8; t++) {
      const uint32x2 v = { pkbf((acc2[t][0]-mu2)*rs2, (acc2[t][1]-mu2)*rs2),
                           pkbf((acc2[t][2]-mu2)*rs2, (acc2[t][3]-mu2)*rs2) };
      *reinterpret_cast<uint32x2*>(hb + c16*136 + 16*t + 4*g) = v;
    }
    asm volatile("s_waitcnt lgkmcnt(0)" ::: "memory");

    // ---- GEMM3': out = z2 @ Wout' + bout' ----
    short8 a3[4];
    #pragma unroll
    for (int ks = 0; ks < 4; ks++)
      a3[ks] = *reinterpret_cast<const short8*>(hb + c16*136 + 32*ks + 8*g);
    const size_t orow = (size_t)(rowbase + c16)*128;
    #pragma unroll
    for (int t = 0; t < 8; t++) {
      f32x4 a3c = *reinterpret_cast<const f32x4*>(boutp + g*32 + t*4);
      #pragma unroll
      for (int ks = 0; ks < 4; ks++) {
        const short8 wf = *reinterpret_cast<const short8*>(woutp + ((t*4 + ks)*64 + lane)*8);
        a3c = __builtin_amdgcn_mfma_f32_16x16x32_bf16(wf, a3[ks], a3c, 0, 0, 0);
      }
      __builtin_nontemporal_store(a3c, reinterpret_cast<f32x4*>(out + orow + 16*t + 4*g));
    }
    asm volatile("s_waitcnt lgkmcnt(0)" ::: "memory");   // a3 reads done before next gr
  }
}

// ---------------- launcher ----------------
extern "C" void kernel_launch(void* const* d_in, const int* in_sizes, int n_in,
                              void* d_out, int out_size, void* d_ws, size_t ws_size,
                              hipStream_t stream)
{
  const float* x     = (const float*)d_in[0];
  const float* emb   = (const float*)d_in[1];
  const float* W_num = (const float*)d_in[2];
  const float* b_num = (const float*)d_in[3];
  const float* W_in  = (const float*)d_in[4];
  const float* b_in  = (const float*)d_in[5];
  const float* W1    = (const float*)d_in[6];
  const float* b1    = (const float*)d_in[7];
  const float* W2    = (const float*)d_in[8];
  const float* b2    = (const float*)d_in[9];
  const float* ln_g  = (const float*)d_in[10];
  const float* ln_b  = (const float*)d_in[11];
  const float* W_out = (const float*)d_in[12];
  const float* b_out = (const float*)d_in[13];
  float* out = (float*)d_out;

  char* ws = (char*)d_ws;
  float*    WLf   = (float*)(ws + 0);         // 131072 B
  float*    Bnum  = (float*)(ws + 131072);    //  10752 B
  float*    bfold = (float*)(ws + 141824);    //   1024 B
  uint16_t* tcatp = (uint16_t*)(ws + 142848); // 256000 B ([2][20][50][64] rotated)
  uint16_t* wl2p  = (uint16_t*)(ws + 398848); //  32768 B
  uint16_t* woutp = (uint16_t*)(ws + 431616); //  32768 B
  uint16_t* a1p   = (uint16_t*)(ws + 464384); //   8192 B
  float*    bf1p  = (float*)(ws + 472576);    //    512 B
  float*    boutp = (float*)(ws + 473088);    //    512 B

  pre1<<<dim3(312), dim3(128), 0, stream>>>(W_num, b_num, W_in, b_in, W1, b1, W2, b2,
                                            W_out, b_out, ln_g, ln_b,
                                            WLf, Bnum, bfold, woutp, boutp);
  pre2<<<dim3(1041), dim3(128), 0, stream>>>(emb, W_in, ln_g, ln_b, WLf, Bnum, bfold,
                                             tcatp, wl2p, bf1p, a1p);
  fused_main<<<dim3(256), dim3(512), 0, stream>>>(x, tcatp, a1p, wl2p, woutp,
                                                  bf1p, boutp, out);
}

// Round 8
// 99.750 us; speedup vs baseline: 2.0429x; 2.0429x over previous
//
#include <hip/hip_runtime.h>
#include <hip/hip_bf16.h>
#include <stdint.h>
#include <stddef.h>

// ---------------------------------------------------------------------------
// FixedEmbedderNN — round 8: LDS-gather, two-kernel split (no cross-half regs).
//  Kernel G: 512 blocks; block = (column-half h, 384 rows). Stages its 125KB
//    half-table in LDS; per 16-row group: numeric MFMA + 2 rotated
//    ds_read_b128 per feature; writes pre-LN h1-half (f32) into d_out (scratch)
//    + per-row (sum,sumsq) partials into ws. Live state per group = 16 VGPR.
//  Kernel T: per-wave 16 rows; LN0 from partials; h1 loaded from d_out in
//    A-frag order; GEMM2' -> LN1 -> LDS roundtrip -> GEMM3' -> overwrite d_out.
//  Table layout [2][20][50][64] u16 with idx-rotated 16B slots:
//    col j=16t+4g+r, h=j>>6, jj=(j>>4)&3: slot s=2g+(jj>>1) stored at (s+c)&7,
//    elem=(jj&1)*4+r. Reader: u0=b128@((2g+idx)&7)*16 -> jj0/jj1,
//    u1=b128@((2g+1+idx)&7)*16 -> jj2/jj3.  Banks spread by idx -> ~2-way.
// ---------------------------------------------------------------------------

typedef __attribute__((ext_vector_type(8))) short short8;
typedef __attribute__((ext_vector_type(4))) float f32x4;
typedef __attribute__((ext_vector_type(2))) uint32_t uint32x2;

#define LN_EPS 1e-5f

__device__ __forceinline__ float bflo(uint32_t u){ union{uint32_t u;float f;} c; c.u = u<<16; return c.f; }
__device__ __forceinline__ float bfhi(uint32_t u){ union{uint32_t u;float f;} c; c.u = u&0xffff0000u; return c.f; }
__device__ __forceinline__ uint16_t f2bf(float f){
  union{ __hip_bfloat16 h; uint16_t u; } c; c.h = __float2bfloat16(f); return c.u;
}
__device__ __forceinline__ uint32_t pkbf(float lo, float hi){
  return (uint32_t)f2bf(lo) | ((uint32_t)f2bf(hi)<<16);
}

// ---------------- precompute kernel 1 (no deps) ----------------
__global__ __launch_bounds__(128) void pre1(
    const float* __restrict__ W_num, const float* __restrict__ b_num,
    const float* __restrict__ W_in,  const float* __restrict__ b_in,
    const float* __restrict__ W1,    const float* __restrict__ b1,
    const float* __restrict__ W2,    const float* __restrict__ b2,
    const float* __restrict__ W_out, const float* __restrict__ b_out,
    const float* __restrict__ ln_g,  const float* __restrict__ ln_b,
    float* __restrict__ WLf,    // [2][128][128]
    float* __restrict__ Bnum,   // [21][128]
    float* __restrict__ bfold,  // [2][128]
    uint16_t* __restrict__ woutp, // Wout' transposed pack [(t*4+ks)*64+lane][8]
    float* __restrict__ boutp)    // bout' permuted [g*32+t*4+r]
{
  const int b = blockIdx.x, j = threadIdx.x;
  if (b < 256) {                       // WL = W1@W2 per layer
    const int l = b >> 7, k = b & 127;
    const float* w1r = W1 + (l*128 + k)*256;
    const float* w2  = W2 + l*256*128;
    float s = 0.f;
    for (int m = 0; m < 256; m++) s = fmaf(w1r[m], w2[m*128 + j], s);
    WLf[(l*128 + k)*128 + j] = s;
  } else if (b < 277) {                // Bnum rows
    const int r = b - 256;
    if (r < 20) {
      const float* wn = W_num + r*32;
      const float* wi = W_in + (size_t)(20 + r)*32*128;
      float s = 0.f;
      for (int e = 0; e < 32; e++) s = fmaf(wn[e], wi[e*128 + j], s);
      Bnum[r*128 + j] = s;
    } else {
      float s = b_in[j];
      for (int f = 0; f < 20; f++) {
        const float* bn = b_num + f*32;
        const float* wi = W_in + (size_t)(20 + f)*32*128;
        for (int e = 0; e < 32; e++) s = fmaf(bn[e], wi[e*128 + j], s);
      }
      Bnum[20*128 + j] = s;
    }
  } else if (b < 279) {                // bfold = b1@W2 + b2
    const int l = b - 277;
    const float* b1r = b1 + l*256;
    const float* w2  = W2 + l*256*128;
    float s = b2[l*128 + j];
    for (int k = 0; k < 256; k++) s = fmaf(b1r[k], w2[k*128 + j], s);
    bfold[l*128 + j] = s;
  } else if (b < 311) {                // woutp: Wout' = diag(g1)@W_out, transposed A-pack
    const int p = b - 279, t = p >> 2, ks = p & 3;
    const int lane = j & 63, rep = j >> 6;
    const int col = 16*t + (lane & 15);
    for (int ii = 0; ii < 4; ii++) {
      const int i = rep*4 + ii;
      const int k = 32*ks + 8*(lane >> 4) + i;
      woutp[((t*4 + ks)*64 + lane)*8 + i] = f2bf(ln_g[128 + k] * W_out[k*128 + col]);
    }
  } else {                             // boutp (permuted): b1n@W_out + b_out
    const int t = (j >> 2) & 7, g = j >> 5, r = j & 3;
    const int col = 16*t + 4*g + r;
    float s = b_out[col];
    for (int k = 0; k < 128; k++) s = fmaf(ln_b[128 + k], W_out[k*128 + col], s);
    boutp[j] = s;
  }
}

// ---------------- precompute kernel 2 (depends on pre1) ----------------
__global__ __launch_bounds__(128) void pre2(
    const float* __restrict__ emb, const float* __restrict__ W_in,
    const float* __restrict__ ln_g, const float* __restrict__ ln_b,
    const float* __restrict__ WLf, const float* __restrict__ Bnum,
    const float* __restrict__ bfold,
    uint16_t* __restrict__ tcatp, // [2][20][50][64] bf16, idx-rotated slots
    uint16_t* __restrict__ wl2p,  // WL1' transposed pack
    float* __restrict__ bf1p,     // bf1' permuted
    uint16_t* __restrict__ a1p)   // A1^T A-frag pack [t*64+lane][8]
{
  const int b = blockIdx.x, j = threadIdx.x;
  __shared__ float sh[128];
  if (b < 1000) {                      // Tcat1 = emb@W_in_slice@WL_0, rotated store
    const int f = b / 50, c = b % 50;
    const float* e  = emb + (f*50 + c)*32;
    const float* wi = W_in + (size_t)f*32*128;
    float s = 0.f;
    for (int k = 0; k < 32; k++) s = fmaf(e[k], wi[k*128 + j], s);
    sh[j] = s;
    __syncthreads();
    float s2 = 0.f;
    for (int k = 0; k < 128; k++) s2 = fmaf(sh[k], WLf[k*128 + j], s2);
    // col j = 16t+4g+r, h=t>>2, jj=t&3: slot s=2g+(jj>>1) at (s+c)&7, elem=(jj&1)*4+r
    const int t = j >> 4, g = (j >> 2) & 3, r = j & 3;
    const int h = t >> 2, jj = t & 3;
    const int slot = (2*g + (jj >> 1) + c) & 7;
    tcatp[((h*20 + f)*50 + c)*64 + slot*8 + (jj & 1)*4 + r] = f2bf(s2);
  } else if (b < 1032) {               // wl2p: WL1' = diag(g0)@WL_1, transposed A-pack
    const int p = b - 1000, t = p >> 2, ks = p & 3;
    const int lane = j & 63, rep = j >> 6;
    const int col = 16*t + (lane & 15);
    const float* wl1 = WLf + 16384;
    for (int ii = 0; ii < 4; ii++) {
      const int i = rep*4 + ii;
      const int k = 32*ks + 8*(lane >> 4) + i;
      wl2p[((t*4 + ks)*64 + lane)*8 + i] = f2bf(ln_g[k] * wl1[k*128 + col]);
    }
  } else if (b == 1032) {              // bf1p (permuted): b0@WL_1 + bfold_1
    const int t = (j >> 2) & 7, g = j >> 5, r = j & 3;
    const int col = 16*t + 4*g + r;
    const float* wl1 = WLf + 16384;
    float s = bfold[128 + col];
    for (int k = 0; k < 128; k++) s = fmaf(ln_b[k], wl1[k*128 + col], s);
    bf1p[j] = s;
  } else {                             // a1p: A1[k][col] = Bnum[k]@WL_0 (+bfold0 @k==20)
    const int t = b - 1033;
    const int lane = j & 63, rep = j >> 6;
    const int col = 16*t + (lane & 15);
    for (int ii = 0; ii < 4; ii++) {
      const int i = rep*4 + ii;
      const int k = 8*(lane >> 4) + i;
      float v = 0.f;
      if (k <= 20) {
        if (k == 20) v = bfold[col];
        for (int m = 0; m < 128; m++) v = fmaf(Bnum[k*128 + m], WLf[m*128 + col], v);
      }
      a1p[(t*64 + lane)*8 + i] = f2bf(v);
    }
  }
}

// ---------------- kernel G: LDS gather, one column half ----------------
// 512 blocks x 512 thr. Block: half h = bid>>8, rows = (bid&255)*384..+383.
__global__ __launch_bounds__(512, 1) void gatherk(
    const float* __restrict__ x,
    const uint16_t* __restrict__ tcatp,
    const uint16_t* __restrict__ a1p,
    float* __restrict__ h1,        // = d_out used as scratch [98304][128] f32
    float2* __restrict__ part)     // [2][98304] (sum, sumsq)
{
  __shared__ uint4 tbl4[8000];                 // 128000 B half table
  __shared__ float xs[8*16*41];                // 20992 B per-wave x staging
  const int tid = threadIdx.x, lane = tid & 63, w = tid >> 6;
  const int g = lane >> 4, c16 = lane & 15;
  const int h = blockIdx.x >> 8, bb = blockIdx.x & 255;
  const char* tbl = (const char*)tbl4;

  // stage this half (125 KB, linear)
  {
    const uint4* src = reinterpret_cast<const uint4*>(tcatp) + h*8000;
    for (int i = tid; i < 8000; i += 512) tbl4[i] = src[i];
  }
  __syncthreads();

  float* xw = xs + w*16*41;
  const float* xr = xw + c16*41;

  for (int gr = 0; gr < 3; gr++) {
    const int rowbase = bb*384 + (w*3 + gr)*16;

    // per-wave x stage (16 rows)
    {
      const float* xsrc = x + (size_t)rowbase*40;
      #pragma unroll
      for (int k = 0; k < 10; k++) {
        const int i = k*64 + lane;
        xw[(i/40)*41 + (i%40)] = xsrc[i];
      }
    }
    asm volatile("s_waitcnt lgkmcnt(0) vmcnt(0)" ::: "memory");

    // numeric via MFMA: acc[jj] = cols 16(4h+jj)+4g+r
    short8 xf;
    #pragma unroll
    for (int i = 0; i < 8; i++) {
      const int k = 8*g + i;
      const float v = (k < 20) ? xr[20 + k] : (k == 20 ? 1.0f : 0.0f);
      ((uint16_t*)&xf)[i] = f2bf(v);
    }
    f32x4 acc[4];
    #pragma unroll
    for (int jj = 0; jj < 4; jj++) {
      const short8 af = *reinterpret_cast<const short8*>(a1p + (((4*h + jj)*64 + lane))*8);
      acc[jj] = __builtin_amdgcn_mfma_f32_16x16x32_bf16(af, xf,
                  (f32x4){0.f,0.f,0.f,0.f}, 0, 0, 0);
    }

    // LDS gather: 2 rotated b128 per feature
    #pragma unroll
    for (int f = 0; f < 20; f++) {
      const int idx = (int)xr[f];
      const char* p = tbl + (uint32_t)(f*50 + idx)*128u;
      const uint4 u0 = *reinterpret_cast<const uint4*>(p + (((2*g + idx) & 7) << 4));
      const uint4 u1 = *reinterpret_cast<const uint4*>(p + (((2*g + 1 + idx) & 7) << 4));
      acc[0][0] += bflo(u0.x); acc[0][1] += bfhi(u0.x);
      acc[0][2] += bflo(u0.y); acc[0][3] += bfhi(u0.y);
      acc[1][0] += bflo(u0.z); acc[1][1] += bfhi(u0.z);
      acc[1][2] += bflo(u0.w); acc[1][3] += bfhi(u0.w);
      acc[2][0] += bflo(u1.x); acc[2][1] += bfhi(u1.x);
      acc[2][2] += bflo(u1.y); acc[2][3] += bfhi(u1.y);
      acc[3][0] += bflo(u1.z); acc[3][1] += bfhi(u1.z);
      acc[3][2] += bflo(u1.w); acc[3][3] += bfhi(u1.w);
    }

    // partials (sum, sumsq) over this half's 64 cols
    float s = 0.f, q = 0.f;
    #pragma unroll
    for (int jj = 0; jj < 4; jj++)
      #pragma unroll
      for (int r = 0; r < 4; r++) { const float v = acc[jj][r]; s += v; q = fmaf(v, v, q); }
    s += __shfl_xor(s, 16); s += __shfl_xor(s, 32);
    q += __shfl_xor(q, 16); q += __shfl_xor(q, 32);
    if ((lane & 48) == 0) part[h*98304 + rowbase + c16] = make_float2(s, q);

    // store pre-LN h1 half (f32) into scratch (=d_out)
    float* hrow = h1 + (size_t)(rowbase + c16)*128 + 64*h + 4*g;
    #pragma unroll
    for (int jj = 0; jj < 4; jj++)
      *reinterpret_cast<f32x4*>(hrow + 16*jj) = acc[jj];
  }
}

// ---------------- kernel T: LN0 + GEMM tail ----------------
// 1536 blocks x 256 thr (4 waves); wave owns 16 rows. h1/out alias (in-place).
__global__ __launch_bounds__(256, 4) void tailk(
    const float* h1,                       // aliases out
    const float2* __restrict__ part,
    const uint16_t* __restrict__ wl2p,
    const uint16_t* __restrict__ woutp,
    const float* __restrict__ bf1p,
    const float* __restrict__ boutp,
    float* out)
{
  __shared__ __align__(16) uint16_t hbuf[4*16*136];
  const int tid = threadIdx.x, lane = tid & 63, w = tid >> 6;
  const int g = lane >> 4, c16 = lane & 15;
  const int row = blockIdx.x*64 + w*16 + c16;
  uint16_t* hb = hbuf + w*16*136;

  // LN0 stats from partials
  const float2 p0 = part[row], p1 = part[98304 + row];
  const float mu = (p0.x + p1.x) * (1.f/128.f);
  const float rs = rsqrtf((p0.y + p1.y)*(1.f/128.f) - mu*mu + LN_EPS);

  // load h1 in A-frag order, normalize, pack bf16
  const float* hrow = h1 + (size_t)row*128;
  short8 a2[4];
  #pragma unroll
  for (int ks = 0; ks < 4; ks++) {
    const f32x4 v0 = *reinterpret_cast<const f32x4*>(hrow + 32*ks + 8*g);
    const f32x4 v1 = *reinterpret_cast<const f32x4*>(hrow + 32*ks + 8*g + 4);
    uint32_t* aw = (uint32_t*)&a2[ks];
    aw[0] = pkbf((v0[0]-mu)*rs, (v0[1]-mu)*rs);
    aw[1] = pkbf((v0[2]-mu)*rs, (v0[3]-mu)*rs);
    aw[2] = pkbf((v1[0]-mu)*rs, (v1[1]-mu)*rs);
    aw[3] = pkbf((v1[2]-mu)*rs, (v1[3]-mu)*rs);
  }

  // GEMM2': acc2 = z1 @ WL1' (+bf1')
  f32x4 acc2[8];
  #pragma unroll
  for (int t = 0; t < 8; t++) {
    acc2[t] = *reinterpret_cast<const f32x4*>(bf1p + g*32 + t*4);
    #pragma unroll
    for (int ks = 0; ks < 4; ks++) {
      const short8 wf = *reinterpret_cast<const short8*>(wl2p + ((t*4 + ks)*64 + lane)*8);
      acc2[t] = __builtin_amdgcn_mfma_f32_16x16x32_bf16(wf, a2[ks], acc2[t], 0, 0, 0);
    }
  }

  // LN1
  float s2 = 0.f;
  #pragma unroll
  for (int t = 0; t < 8; t++) { s2 += acc2[t][0]+acc2[t][1]+acc2[t][2]+acc2[t][3]; }
  s2 += __shfl_xor(s2, 16); s2 += __shfl_xor(s2, 32);
  const float mu2 = s2 * (1.f/128.f);
  float q2 = 0.f;
  #pragma unroll
  for (int t = 0; t < 8; t++)
    #pragma unroll
    for (int r = 0; r < 4; r++) { const float d = acc2[t][r]-mu2; q2 = fmaf(d, d, q2); }
  q2 += __shfl_xor(q2, 16); q2 += __shfl_xor(q2, 32);
  const float rs2 = rsqrtf(q2*(1.f/128.f) + LN_EPS);

  #pragma unroll
  for (int t = 0; t < 8; t++) {
    const uint32x2 v = { pkbf((acc2[t][0]-mu2)*rs2, (acc2[t][1]-mu2)*rs2),
                         pkbf((acc2[t][2]-mu2)*rs2, (acc2[t][3]-mu2)*rs2) };
    *reinterpret_cast<uint32x2*>(hb + c16*136 + 16*t + 4*g) = v;
  }
  asm volatile("s_waitcnt lgkmcnt(0)" ::: "memory");

  // GEMM3': out = z2 @ Wout' + bout'  (overwrites h1 rows already consumed)
  short8 a3[4];
  #pragma unroll
  for (int ks = 0; ks < 4; ks++)
    a3[ks] = *reinterpret_cast<const short8*>(hb + c16*136 + 32*ks + 8*g);
  float* orow = out + (size_t)row*128;
  #pragma unroll
  for (int t = 0; t < 8; t++) {
    f32x4 a3c = *reinterpret_cast<const f32x4*>(boutp + g*32 + t*4);
    #pragma unroll
    for (int ks = 0; ks < 4; ks++) {
      const short8 wf = *reinterpret_cast<const short8*>(woutp + ((t*4 + ks)*64 + lane)*8);
      a3c = __builtin_amdgcn_mfma_f32_16x16x32_bf16(wf, a3[ks], a3c, 0, 0, 0);
    }
    *reinterpret_cast<f32x4*>(orow + 16*t + 4*g) = a3c;
  }
}

// ---------------- launcher ----------------
extern "C" void kernel_launch(void* const* d_in, const int* in_sizes, int n_in,
                              void* d_out, int out_size, void* d_ws, size_t ws_size,
                              hipStream_t stream)
{
  const float* x     = (const float*)d_in[0];
  const float* emb   = (const float*)d_in[1];
  const float* W_num = (const float*)d_in[2];
  const float* b_num = (const float*)d_in[3];
  const float* W_in  = (const float*)d_in[4];
  const float* b_in  = (const float*)d_in[5];
  const float* W1    = (const float*)d_in[6];
  const float* b1    = (const float*)d_in[7];
  const float* W2    = (const float*)d_in[8];
  const float* b2    = (const float*)d_in[9];
  const float* ln_g  = (const float*)d_in[10];
  const float* ln_b  = (const float*)d_in[11];
  const float* W_out = (const float*)d_in[12];
  const float* b_out = (const float*)d_in[13];
  float* out = (float*)d_out;

  char* ws = (char*)d_ws;
  float*    WLf   = (float*)(ws + 0);         // 131072 B
  float*    Bnum  = (float*)(ws + 131072);    //  10752 B
  float*    bfold = (float*)(ws + 141824);    //   1024 B
  uint16_t* tcatp = (uint16_t*)(ws + 142848); // 256000 B ([2][20][50][64] rotated)
  uint16_t* wl2p  = (uint16_t*)(ws + 398848); //  32768 B
  uint16_t* woutp = (uint16_t*)(ws + 431616); //  32768 B
  uint16_t* a1p   = (uint16_t*)(ws + 464384); //   8192 B
  float*    bf1p  = (float*)(ws + 472576);    //    512 B
  float*    boutp = (float*)(ws + 473088);    //    512 B
  float2*   part  = (float2*)(ws + 473600);   // 2*98304*8 = 1572864 B

  pre1<<<dim3(312), dim3(128), 0, stream>>>(W_num, b_num, W_in, b_in, W1, b1, W2, b2,
                                            W_out, b_out, ln_g, ln_b,
                                            WLf, Bnum, bfold, woutp, boutp);
  pre2<<<dim3(1041), dim3(128), 0, stream>>>(emb, W_in, ln_g, ln_b, WLf, Bnum, bfold,
                                             tcatp, wl2p, bf1p, a1p);
  gatherk<<<dim3(512), dim3(512), 0, stream>>>(x, tcatp, a1p, out, part);
  tailk<<<dim3(1536), dim3(256), 0, stream>>>(out, part, wl2p, woutp, bf1p, boutp, out);
}